// Round 4
// baseline (43.902 us; speedup 1.0000x reference)
//
#include <hip/hip_runtime.h>
#include <math.h>

// Problem geometry (fixed by the reference): probability [64, 2, 512, 512] fp32.
constexpr int B       = 64;
constexpr int HW      = 512 * 512;        // pixels per (batch, channel)
constexpr int CHUNKS  = 32;               // blocks per batch -> 2048 blocks total
constexpr int PIX     = HW / CHUNKS;      // 8192 pixels per block
constexpr int THREADS = 256;
constexpr int NBLK    = B * CHUNKS;       // 2048
constexpr int ITER    = PIX / 4 / THREADS; // 8 float4 iterations per thread

// d_ws layout: [0 .. NBLK) float partials | byte 8192: u32 arrival counter.
// NO fences anywhere: all cross-block communication is relaxed agent-scope
// atomics (coherence-point ops, no L2 writeback — R2's 5x regression was the
// per-block __threadfence, not fusion itself).

__global__ __launch_bounds__(THREADS)
void lb_fused(const float* __restrict__ prob, float* __restrict__ partials,
              unsigned* __restrict__ counter, float* __restrict__ out) {
    const int blk = blockIdx.x;
    const int b   = blk >> 5;             // blk / CHUNKS
    const int c   = blk & (CHUNKS - 1);   // blk % CHUNKS

    const float4* __restrict__ x0 =
        reinterpret_cast<const float4*>(prob + (size_t)b * 2 * HW + (size_t)c * PIX);
    const float4* __restrict__ x1 =
        reinterpret_cast<const float4*>(prob + (size_t)b * 2 * HW + HW + (size_t)c * PIX);

    // Load-first register staging: all 16 float4 loads in flight before compute.
    float4 a[ITER], d[ITER];
    #pragma unroll
    for (int it = 0; it < ITER; ++it) {
        const int i = it * THREADS + threadIdx.x;
        a[it] = x0[i];
        d[it] = x1[i];
    }

    float acc = 0.f;
    #pragma unroll
    for (int it = 0; it < ITER; ++it) {
        // sigmoid(d-a) = 1/(1+exp(a-d)); fast exp + rcp (abs threshold 312 — huge slack)
        acc += __builtin_amdgcn_rcpf(1.f + __expf(a[it].x - d[it].x));
        acc += __builtin_amdgcn_rcpf(1.f + __expf(a[it].y - d[it].y));
        acc += __builtin_amdgcn_rcpf(1.f + __expf(a[it].z - d[it].z));
        acc += __builtin_amdgcn_rcpf(1.f + __expf(a[it].w - d[it].w));
    }

    // wave64 reduction, then cross-wave via LDS
    #pragma unroll
    for (int off = 32; off > 0; off >>= 1)
        acc += __shfl_down(acc, off, 64);

    __shared__ float sdata[THREADS / 64];
    __shared__ int   isLastSh;
    const int lane = threadIdx.x & 63;
    const int wid  = threadIdx.x >> 6;
    if (lane == 0) sdata[wid] = acc;
    __syncthreads();

    if (threadIdx.x == 0) {
        float s = 0.f;
        #pragma unroll
        for (int w = 0; w < THREADS / 64; ++w) s += sdata[w];
        // publish partial at the coherence point (relaxed, agent scope — no flush)
        __hip_atomic_store(&partials[blk], s, __ATOMIC_RELAXED,
                           __HIP_MEMORY_SCOPE_AGENT);
        // ensure the store has retired at the coherence point before arrival
        asm volatile("s_waitcnt vmcnt(0)" ::: "memory");
        unsigned old = __hip_atomic_fetch_add(counter, 1u, __ATOMIC_RELAXED,
                                              __HIP_MEMORY_SCOPE_AGENT);
        isLastSh = (old == (unsigned)(NBLK - 1));
    }
    __syncthreads();
    if (!isLastSh) return;

    // ---- last block: deterministic double-precision finale (256 threads) ----
    const int t = threadIdx.x;
    const int bb = t >> 2;                // batch 0..63
    const int q  = t & 3;                 // quarter 0..3
    double ps = 0.0;
    #pragma unroll
    for (int k = 0; k < 8; ++k) {
        float p = __hip_atomic_load(&partials[bb * CHUNKS + q * 8 + k],
                                    __ATOMIC_RELAXED, __HIP_MEMORY_SCOPE_AGENT);
        ps += (double)p;
    }
    ps += __shfl_xor(ps, 1, 64);
    ps += __shfl_xor(ps, 2, 64);

    __shared__ double s_sh[B];
    if (q == 0) s_sh[bb] = ps;
    __syncthreads();

    if (t >= 64) return;
    const double s = s_sh[t];             // lane t = batch t

    const double LOW  = 131050.0;
    const double HIGH = 131100.0;

    // low_vec_sum = sum over the whole batch of (s - LOW)^2
    double dl  = s - LOW;
    double lvs = dl * dl;
    #pragma unroll
    for (int off = 32; off > 0; off >>= 1) lvs += __shfl_xor(lvs, off, 64);

    // Faithful reproduction of the reference's branchy contributions.
    double contrib, count;
    if (s >= HIGH)      { double dd = s - HIGH; contrib = dd * dd; count = 1.0; }
    else if (s <= LOW)  { contrib = lvs;                           count = (double)B; }
    else                { contrib = 0.0;                           count = 1.0; }

    double cs = contrib, cn = count;
    #pragma unroll
    for (int off = 32; off > 0; off >>= 1) {
        cs += __shfl_xor(cs, off, 64);
        cn += __shfl_xor(cn, off, 64);
    }
    if (t == 0) out[0] = (float)(cs / cn);
}

extern "C" void kernel_launch(void* const* d_in, const int* in_sizes, int n_in,
                              void* d_out, int out_size, void* d_ws, size_t ws_size,
                              hipStream_t stream) {
    const float* prob     = (const float*)d_in[0];
    float*       out      = (float*)d_out;
    float*       partials = (float*)d_ws;
    unsigned*    counter  = (unsigned*)((char*)d_ws + NBLK * sizeof(float));

    // zero the arrival counter each call (graph-capturable async op)
    hipMemsetAsync(counter, 0, sizeof(unsigned), stream);
    lb_fused<<<NBLK, THREADS, 0, stream>>>(prob, partials, counter, out);
}

// Round 5
// 32.368 us; speedup vs baseline: 1.3563x; 1.3563x over previous
//
#include <hip/hip_runtime.h>
#include <math.h>

// Problem geometry (fixed by the reference): probability [64, 2, 512, 512] fp32.
constexpr int B       = 64;
constexpr int HW      = 512 * 512;        // pixels per (batch, channel)
constexpr int CHUNKS  = 32;               // blocks per batch -> 2048 blocks total
constexpr int PIX     = HW / CHUNKS;      // 8192 pixels per block
constexpr int THREADS = 256;
constexpr int NBLK    = B * CHUNKS;       // 2048
constexpr int ITER    = PIX / 4 / THREADS; // 8 float4 iterations per thread
constexpr int L1N     = 32;               // level-1 counters (64 blocks each)

// d_ws layout:
//   [0, 8192)            float partials[2048]
//   [8192, 8192+4096)    u32 l1[32], one per 128 B line (stride 32 u32)
//   [12288, 12288+4)     u32 l2
// All cross-block comms are RELAXED agent-scope atomics (no fences — R2's 5x
// regression was per-block __threadfence; R4's +16us was 2048-deep RMW chain
// on ONE counter line. Hierarchical fan-in caps any chain at 64.)

__global__ __launch_bounds__(THREADS)
void lb_fused(const float* __restrict__ prob, float* __restrict__ partials,
              unsigned* __restrict__ l1, unsigned* __restrict__ l2,
              float* __restrict__ out) {
    const int blk = blockIdx.x;
    const int b   = blk >> 5;             // blk / CHUNKS
    const int c   = blk & (CHUNKS - 1);   // blk % CHUNKS

    const float4* __restrict__ x0 =
        reinterpret_cast<const float4*>(prob + (size_t)b * 2 * HW + (size_t)c * PIX);
    const float4* __restrict__ x1 =
        reinterpret_cast<const float4*>(prob + (size_t)b * 2 * HW + HW + (size_t)c * PIX);

    // Load-first register staging: all 16 float4 loads in flight before compute.
    float4 a[ITER], d[ITER];
    #pragma unroll
    for (int it = 0; it < ITER; ++it) {
        const int i = it * THREADS + threadIdx.x;
        a[it] = x0[i];
        d[it] = x1[i];
    }

    float acc = 0.f;
    #pragma unroll
    for (int it = 0; it < ITER; ++it) {
        // sigmoid(d-a) = 1/(1+exp(a-d)); fast exp + rcp (abs threshold 312)
        acc += __builtin_amdgcn_rcpf(1.f + __expf(a[it].x - d[it].x));
        acc += __builtin_amdgcn_rcpf(1.f + __expf(a[it].y - d[it].y));
        acc += __builtin_amdgcn_rcpf(1.f + __expf(a[it].z - d[it].z));
        acc += __builtin_amdgcn_rcpf(1.f + __expf(a[it].w - d[it].w));
    }

    // wave64 reduction, then cross-wave via LDS
    #pragma unroll
    for (int off = 32; off > 0; off >>= 1)
        acc += __shfl_down(acc, off, 64);

    __shared__ float sdata[THREADS / 64];
    __shared__ int   isLastSh;
    const int lane = threadIdx.x & 63;
    const int wid  = threadIdx.x >> 6;
    if (lane == 0) sdata[wid] = acc;
    __syncthreads();

    if (threadIdx.x == 0) {
        float s = 0.f;
        #pragma unroll
        for (int w = 0; w < THREADS / 64; ++w) s += sdata[w];
        // publish partial at the coherence point (relaxed agent — no flush)
        __hip_atomic_store(&partials[blk], s, __ATOMIC_RELAXED,
                           __HIP_MEMORY_SCOPE_AGENT);
        // store retired at coherence point before arrival
        asm volatile("s_waitcnt vmcnt(0)" ::: "memory");
        int last = 0;
        unsigned old = __hip_atomic_fetch_add(&l1[(blk >> 6) * 32], 1u,
                                              __ATOMIC_RELAXED,
                                              __HIP_MEMORY_SCOPE_AGENT);
        if (old == 63u) {
            unsigned old2 = __hip_atomic_fetch_add(l2, 1u, __ATOMIC_RELAXED,
                                                   __HIP_MEMORY_SCOPE_AGENT);
            last = (old2 == (unsigned)(L1N - 1));
        }
        isLastSh = last;
    }
    __syncthreads();
    if (!isLastSh) return;

    // ---- last block: deterministic double-precision finale (256 threads) ----
    const int t  = threadIdx.x;
    const int bb = t >> 2;                // batch 0..63
    const int q  = t & 3;                 // quarter 0..3
    double ps = 0.0;
    #pragma unroll
    for (int k = 0; k < 8; ++k) {
        float p = __hip_atomic_load(&partials[bb * CHUNKS + q * 8 + k],
                                    __ATOMIC_RELAXED, __HIP_MEMORY_SCOPE_AGENT);
        ps += (double)p;
    }
    ps += __shfl_xor(ps, 1, 64);
    ps += __shfl_xor(ps, 2, 64);

    __shared__ double s_sh[B];
    if (q == 0) s_sh[bb] = ps;
    __syncthreads();

    if (t >= 64) return;
    const double s = s_sh[t];             // lane t = batch t

    const double LOW  = 131050.0;
    const double HIGH = 131100.0;

    // low_vec_sum = sum over the whole batch of (s - LOW)^2
    double dl  = s - LOW;
    double lvs = dl * dl;
    #pragma unroll
    for (int off = 32; off > 0; off >>= 1) lvs += __shfl_xor(lvs, off, 64);

    // Faithful reproduction of the reference's branchy contributions.
    double contrib, count;
    if (s >= HIGH)      { double dd = s - HIGH; contrib = dd * dd; count = 1.0; }
    else if (s <= LOW)  { contrib = lvs;                           count = (double)B; }
    else                { contrib = 0.0;                           count = 1.0; }

    double cs = contrib, cn = count;
    #pragma unroll
    for (int off = 32; off > 0; off >>= 1) {
        cs += __shfl_xor(cs, off, 64);
        cn += __shfl_xor(cn, off, 64);
    }
    if (t == 0) out[0] = (float)(cs / cn);
}

extern "C" void kernel_launch(void* const* d_in, const int* in_sizes, int n_in,
                              void* d_out, int out_size, void* d_ws, size_t ws_size,
                              hipStream_t stream) {
    const float* prob     = (const float*)d_in[0];
    float*       out      = (float*)d_out;
    float*       partials = (float*)d_ws;
    unsigned*    l1       = (unsigned*)((char*)d_ws + 8192);
    unsigned*    l2       = (unsigned*)((char*)d_ws + 8192 + 4096);

    // zero all arrival counters each call (one graph-capturable async op)
    hipMemsetAsync((char*)d_ws + 8192, 0, 4096 + 128, stream);
    lb_fused<<<NBLK, THREADS, 0, stream>>>(prob, partials, l1, l2, out);
}

// Round 6
// 27.049 us; speedup vs baseline: 1.6230x; 1.1966x over previous
//
#include <hip/hip_runtime.h>
#include <math.h>

// Problem geometry (fixed by the reference): probability [64, 2, 512, 512] fp32.
constexpr int B       = 64;
constexpr int HW      = 512 * 512;        // pixels per (batch, channel)
constexpr int CHUNKS  = 32;               // blocks per batch -> 2048 blocks total
constexpr int PIX     = HW / CHUNKS;      // 8192 pixels per block
constexpr int THREADS = 256;
constexpr int NBLK    = B * CHUNKS;       // 2048
constexpr int ITER    = PIX / 4 / THREADS; // 8 float4 iterations per thread

// Kernel 1: per-block partial sums of sigmoid(x1 - x0) = softmax(axis=1)[ch 1].
// Load-first register staging: all 16 float4 loads in flight before compute.
// (Best measured variant — R3, 27.2 us end-to-end.)
__global__ __launch_bounds__(THREADS)
void lb_partials(const float* __restrict__ prob, float* __restrict__ partials) {
    const int blk = blockIdx.x;
    const int b   = blk >> 5;             // blk / CHUNKS
    const int c   = blk & (CHUNKS - 1);   // blk % CHUNKS

    const float4* __restrict__ x0 =
        reinterpret_cast<const float4*>(prob + (size_t)b * 2 * HW + (size_t)c * PIX);
    const float4* __restrict__ x1 =
        reinterpret_cast<const float4*>(prob + (size_t)b * 2 * HW + HW + (size_t)c * PIX);

    float4 a[ITER], d[ITER];
    #pragma unroll
    for (int it = 0; it < ITER; ++it) {
        const int i = it * THREADS + threadIdx.x;
        a[it] = x0[i];
        d[it] = x1[i];
    }

    float acc = 0.f;
    #pragma unroll
    for (int it = 0; it < ITER; ++it) {
        // sigmoid(d-a) = 1/(1+exp(a-d)); fast exp + rcp (abs threshold 312 — huge slack)
        acc += __builtin_amdgcn_rcpf(1.f + __expf(a[it].x - d[it].x));
        acc += __builtin_amdgcn_rcpf(1.f + __expf(a[it].y - d[it].y));
        acc += __builtin_amdgcn_rcpf(1.f + __expf(a[it].z - d[it].z));
        acc += __builtin_amdgcn_rcpf(1.f + __expf(a[it].w - d[it].w));
    }

    // wave64 reduction, then cross-wave via LDS
    #pragma unroll
    for (int off = 32; off > 0; off >>= 1)
        acc += __shfl_down(acc, off, 64);

    __shared__ float sdata[THREADS / 64];
    const int lane = threadIdx.x & 63;
    const int wid  = threadIdx.x >> 6;
    if (lane == 0) sdata[wid] = acc;
    __syncthreads();
    if (threadIdx.x == 0) {
        float s = 0.f;
        #pragma unroll
        for (int w = 0; w < THREADS / 64; ++w) s += sdata[w];
        partials[blk] = s;
    }
}

// Kernel 2: ONE wave. Lane b = batch b: 8 independent float4 loads (all in
// flight -> single memory round-trip), double-precision sum, in-wave finale.
// No LDS, no __syncthreads.
__global__ __launch_bounds__(64)
void lb_final(const float* __restrict__ partials, float* __restrict__ out) {
    const int b = threadIdx.x;            // 0..63 == batch index
    const float4* __restrict__ p4 =
        reinterpret_cast<const float4*>(partials + b * CHUNKS);

    float4 v[8];
    #pragma unroll
    for (int k = 0; k < 8; ++k) v[k] = p4[k];   // 8 loads issued back-to-back

    double s = 0.0;
    #pragma unroll
    for (int k = 0; k < 8; ++k) {
        s += (double)v[k].x;
        s += (double)v[k].y;
        s += (double)v[k].z;
        s += (double)v[k].w;
    }

    const double LOW  = 131050.0;
    const double HIGH = 131100.0;

    // low_vec_sum = sum over the whole batch of (s - LOW)^2
    double dl  = s - LOW;
    double lvs = dl * dl;
    #pragma unroll
    for (int off = 32; off > 0; off >>= 1) lvs += __shfl_xor(lvs, off, 64);

    // Faithful reproduction of the reference's branchy contributions.
    double contrib, count;
    if (s >= HIGH)      { double dd = s - HIGH; contrib = dd * dd; count = 1.0; }
    else if (s <= LOW)  { contrib = lvs;                           count = (double)B; }
    else                { contrib = 0.0;                           count = 1.0; }

    double cs = contrib, cn = count;
    #pragma unroll
    for (int off = 32; off > 0; off >>= 1) {
        cs += __shfl_xor(cs, off, 64);
        cn += __shfl_xor(cn, off, 64);
    }
    if (b == 0) out[0] = (float)(cs / cn);
}

extern "C" void kernel_launch(void* const* d_in, const int* in_sizes, int n_in,
                              void* d_out, int out_size, void* d_ws, size_t ws_size,
                              hipStream_t stream) {
    const float* prob     = (const float*)d_in[0];
    float*       out      = (float*)d_out;
    float*       partials = (float*)d_ws;   // 2048 floats, written before read

    lb_partials<<<NBLK, THREADS, 0, stream>>>(prob, partials);
    lb_final<<<1, 64, 0, stream>>>(partials, out);
}